// Round 4
// baseline (211.491 us; speedup 1.0000x reference)
//
#include <hip/hip_runtime.h>
#include <hip/hip_bf16.h>

// Problem constants
#define B 256
#define S 256
#define H 768
#define C 150
#define H4 192              // H / 4 (float4 columns)

#define NPOOL 1024
#define NTM   152
#define NGEMM 256
#define NBLK  (NPOOL + NTM + NGEMM)

// ws layout (bytes):
//  part1   : 0        .. 3145728   [256][4][768] f32 pool partials
//  dp      : 3145728  .. 4374528   [8][256][150] f32 score-dot partials
//  tx_part : 4374528  .. 4382720   [8][256] f32
//  tm_part : 4382720  .. 4387584   [8][152] f32
//  cntp    : 4387584  .. 4391680   [256][4] i32 mask counts
//  cnt     : 4391680  .. 4391936   flags: [0..31] row-tile pool counters,
//                                  [32] tm-done, [33] gemm-done
#define CNT_OFF 4391680

__global__ __launch_bounds__(192) void kFused(const float* __restrict__ lhs,
                                              const int* __restrict__ mask,
                                              const float* __restrict__ means,
                                              const float* __restrict__ cov,
                                              float* __restrict__ part1,
                                              int* __restrict__ cntp,
                                              float* __restrict__ tm_part,
                                              float* __restrict__ dp,
                                              float* __restrict__ tx_part,
                                              int* __restrict__ cnt,
                                              float* __restrict__ out) {
    const int bid = blockIdx.x;
    const int t = threadIdx.x;
    __shared__ float xsl[8 * H];        // 24 KB: msk (pool) / means rows (tm) / prelogits (gemm)
    __shared__ float4 red2[8][24];      // 3 KB: k-group reduce (gemm) / sv (scores)
    __shared__ float4 xsf[8][24];       // 3 KB: xS col-slice (gemm) / si (scores)
    __shared__ float sred[8][3];

    if (bid < NPOOL) {
        // ================= pool partial: b = bid>>2, 64-row chunk =================
        const int b = bid >> 2, chunk = bid & 3, s0 = chunk * 64;
        float* msk = xsl;
        if (t < 64) {
            const int mv = mask[b * S + s0 + t];
            msk[t] = (float)mv;
            int v = mv;
#pragma unroll
            for (int off = 32; off > 0; off >>= 1) v += __shfl_down(v, off, 64);
            if (t == 0) cntp[b * 4 + chunk] = v;
        }
        __syncthreads();

        const float4* src = (const float4*)lhs + (size_t)(b * S + s0) * H4 + t;
        float4 acc = make_float4(0.f, 0.f, 0.f, 0.f);
#pragma unroll 8
        for (int s = 0; s < 64; ++s) {
            const float m = msk[s];
            const float4 v = src[(size_t)s * H4];
            acc.x += v.x * m; acc.y += v.y * m; acc.z += v.z * m; acc.w += v.w * m;
        }
        ((float4*)part1)[(size_t)(b * 4 + chunk) * H4 + t] = acc;

        __syncthreads();
        if (t == 0) {
            __threadfence();
            __hip_atomic_fetch_add(&cnt[b >> 3], 1, __ATOMIC_RELEASE, __HIP_MEMORY_SCOPE_AGENT);
        }
    } else if (bid < NPOOL + NTM) {
        // ================= t_m partials: means @ cov . means =================
        const int idx = bid - NPOOL;
        const int rt = idx >> 3, cs = idx & 7;
        const int r0 = rt * 8, cb = cs * 24;
        const int kg = t / 24, c4 = t % 24;

        for (int r = 0; r < 8; ++r) {
            const int row = r0 + r;
            float4 v = make_float4(0.f, 0.f, 0.f, 0.f);
            if (row < C) v = ((const float4*)means)[(size_t)row * H4 + t];
            ((float4*)xsl)[r * H4 + t] = v;
        }
        __syncthreads();

        float4 acc[8];
#pragma unroll
        for (int r = 0; r < 8; ++r) acc[r] = make_float4(0.f, 0.f, 0.f, 0.f);
        const float4* cov4 = (const float4*)cov + cb + c4;
#pragma unroll 4
        for (int kk = 0; kk < 96; ++kk) {
            const int k = kg * 96 + kk;
            const float4 cv = cov4[(size_t)k * H4];
#pragma unroll
            for (int r = 0; r < 8; ++r) {
                const float xv = xsl[r * H + k];
                acc[r].x += xv * cv.x; acc[r].y += xv * cv.y;
                acc[r].z += xv * cv.z; acc[r].w += xv * cv.w;
            }
        }
        const int w = t >> 6;
#pragma unroll
        for (int r = 0; r < 8; ++r) {
            const float4 mu = ((float4*)xsl)[r * H4 + cb + c4];
            float pd = acc[r].x * mu.x + acc[r].y * mu.y + acc[r].z * mu.z + acc[r].w * mu.w;
#pragma unroll
            for (int off = 32; off > 0; off >>= 1) pd += __shfl_down(pd, off, 64);
            if ((t & 63) == 0) sred[r][w] = pd;
        }
        __syncthreads();
        if (t < 8) {
            const int row = r0 + t;
            if (row < C)
                tm_part[cs * 152 + row] = sred[t][0] + sred[t][1] + sred[t][2];
        }
        __syncthreads();
        if (t == 0) {
            __threadfence();
            __hip_atomic_fetch_add(&cnt[32], 1, __ATOMIC_RELEASE, __HIP_MEMORY_SCOPE_AGENT);
        }
    } else {
        // ================= xS GEMM + t_x + score-dot partials, then scores =================
        const int idx = bid - (NPOOL + NTM);
        const int rt = idx >> 3, cs = idx & 7;
        const int r0 = rt * 8, cb = cs * 24;
        const int kg = t / 24, c4 = t % 24;

        // wait for the 32 pool blocks covering rows r0..r0+7
        if (t == 0) {
            while (__hip_atomic_load(&cnt[rt], __ATOMIC_ACQUIRE, __HIP_MEMORY_SCOPE_AGENT) < 32)
                __builtin_amdgcn_s_sleep(2);
        }
        __syncthreads();

        // pool finalize into LDS
        for (int r = 0; r < 8; ++r) {
            const int row = r0 + r;
            const int cnt4 = cntp[row * 4] + cntp[row * 4 + 1] + cntp[row * 4 + 2] + cntp[row * 4 + 3];
            const float inv = 1.0f / fmaxf((float)cnt4, 1e-9f);
            const float4* p = (const float4*)part1 + (size_t)row * 4 * H4 + t;
            const float4 a = p[0], b2 = p[H4], c2 = p[2 * H4], d2 = p[3 * H4];
            float4 v;
            v.x = (a.x + b2.x + c2.x + d2.x) * inv;
            v.y = (a.y + b2.y + c2.y + d2.y) * inv;
            v.z = (a.z + b2.z + c2.z + d2.z) * inv;
            v.w = (a.w + b2.w + c2.w + d2.w) * inv;
            ((float4*)xsl)[r * H4 + t] = v;
        }
        __syncthreads();

        float4 acc[8];
#pragma unroll
        for (int r = 0; r < 8; ++r) acc[r] = make_float4(0.f, 0.f, 0.f, 0.f);
        const float4* cov4 = (const float4*)cov + cb + c4;
#pragma unroll 4
        for (int kk = 0; kk < 96; ++kk) {
            const int k = kg * 96 + kk;
            const float4 cv = cov4[(size_t)k * H4];
#pragma unroll
            for (int r = 0; r < 8; ++r) {
                const float xv = xsl[r * H + k];
                acc[r].x += xv * cv.x; acc[r].y += xv * cv.y;
                acc[r].z += xv * cv.z; acc[r].w += xv * cv.w;
            }
        }

        float pdr[8];
#pragma unroll
        for (int r = 0; r < 8; ++r) pdr[r] = 0.f;
        for (int r = 0; r < 8; ++r) {
            red2[kg][c4] = acc[r];
            __syncthreads();
            if (kg == 0) {
                float4 s = red2[0][c4];
#pragma unroll
                for (int g = 1; g < 8; ++g) {
                    const float4 q = red2[g][c4];
                    s.x += q.x; s.y += q.y; s.z += q.z; s.w += q.w;
                }
                xsf[r][c4] = s;
                const float4 xv = ((float4*)xsl)[r * H4 + cb + c4];
                pdr[r] = s.x * xv.x + s.y * xv.y + s.z * xv.z + s.w * xv.w;
            }
            __syncthreads();
        }

        // t_x partials (lanes 0..23 hold contributions)
        if (t < 64) {
#pragma unroll
            for (int r = 0; r < 8; ++r) {
                float v = (t < 24) ? pdr[r] : 0.f;
#pragma unroll
                for (int off = 16; off > 0; off >>= 1) v += __shfl_down(v, off, 32);
                if (t == 0) tx_part[cs * 256 + r0 + r] = v;
            }
        }

        // score-dot partials: thread t = class c
        if (t < C) {
            const float4* mu4 = (const float4*)means + (size_t)t * H4 + cb;
            float a8[8];
#pragma unroll
            for (int r = 0; r < 8; ++r) a8[r] = 0.f;
#pragma unroll 4
            for (int j = 0; j < 24; ++j) {
                const float4 mv = mu4[j];
#pragma unroll
                for (int r = 0; r < 8; ++r) {
                    const float4 x = xsf[r][j];
                    a8[r] += mv.x * x.x + mv.y * x.y + mv.z * x.z + mv.w * x.w;
                }
            }
#pragma unroll
            for (int r = 0; r < 8; ++r)
                dp[((size_t)(cs * 256) + (r0 + r)) * 150 + t] = a8[r];
        }

        // signal gemm done, wait for ALL gemm + tm blocks
        __syncthreads();
        if (t == 0) {
            __threadfence();
            __hip_atomic_fetch_add(&cnt[33], 1, __ATOMIC_RELEASE, __HIP_MEMORY_SCOPE_AGENT);
            while (__hip_atomic_load(&cnt[33], __ATOMIC_ACQUIRE, __HIP_MEMORY_SCOPE_AGENT) < NGEMM ||
                   __hip_atomic_load(&cnt[32], __ATOMIC_ACQUIRE, __HIP_MEMORY_SCOPE_AGENT) < NTM)
                __builtin_amdgcn_s_sleep(2);
        }
        __syncthreads();

        // ================= scores + argmin for b = idx =================
        const int b = idx;
        float* sv = (float*)red2;
        int* si = (int*)xsf;
        float sc = INFINITY;
        if (t < C) {
            float d = 0.f;
#pragma unroll
            for (int j = 0; j < 8; ++j) d += dp[((size_t)(j * 256) + b) * 150 + t];
            float tx = 0.f;
#pragma unroll
            for (int j = 0; j < 8; ++j) tx += tx_part[j * 256 + b];
            float tm = 0.f;
#pragma unroll
            for (int j = 0; j < 8; ++j) tm += tm_part[j * 152 + t];
            sc = tx - 2.0f * d + tm;
            out[B + (size_t)t * B + b] = sc;
        }
        sv[t] = sc;
        si[t] = (t < C) ? t : 0x7fffffff;
        __syncthreads();
#pragma unroll
        for (int off = 96; off >= 3; off >>= 1) {
            if (t < off) {
                const float ov = sv[t + off];
                const int oi = si[t + off];
                if (ov < sv[t] || (ov == sv[t] && oi < si[t])) { sv[t] = ov; si[t] = oi; }
            }
            __syncthreads();
        }
        if (t == 0) {
            float bv = sv[0];
            int bi = si[0];
#pragma unroll
            for (int j = 1; j < 3; ++j)
                if (sv[j] < bv || (sv[j] == bv && si[j] < bi)) { bv = sv[j]; bi = si[j]; }
            out[b] = (float)bi;
        }
    }
}

extern "C" void kernel_launch(void* const* d_in, const int* in_sizes, int n_in,
                              void* d_out, int out_size, void* d_ws, size_t ws_size,
                              hipStream_t stream) {
    const float* lhs   = (const float*)d_in[0];   // [B,S,H] f32
    const int*   mask  = (const int*)d_in[1];     // [B,S] i32
    const float* means = (const float*)d_in[2];   // [C,H] f32
    const float* cov   = (const float*)d_in[3];   // [H,H] f32
    float* out = (float*)d_out;

    char* ws = (char*)d_ws;
    float* part1   = (float*)(ws + 0);
    float* dp      = (float*)(ws + 3145728);
    float* tx_part = (float*)(ws + 4374528);
    float* tm_part = (float*)(ws + 4382720);
    int*   cntp    = (int*)  (ws + 4387584);
    int*   cnt     = (int*)  (ws + CNT_OFF);

    hipMemsetAsync(cnt, 0, 256, stream);
    kFused<<<dim3(NBLK), 192, 0, stream>>>(lhs, mask, means, cov, part1, cntp,
                                           tm_part, dp, tx_part, cnt, out);
}

// Round 5
// 59.219 us; speedup vs baseline: 3.5713x; 3.5713x over previous
//
#include <hip/hip_runtime.h>
#include <hip/hip_bf16.h>

// Problem constants
#define B 256
#define S 256
#define H 768
#define C 150
#define H4 192              // H / 4 (float4 columns)

// ws layout (bytes):
//  part1   : 0        .. 3145728   [256][4][768] f32 pool partials
//  dp      : 3145728  .. 4374528   [8][256][150] f32 score-dot partials
//  tx_part : 4374528  .. 4382720   [8][256] f32
//  tm_part : 4382720  .. 4387584   [8][152] f32
//  cntp    : 4387584  .. 4391680   [256][4] i32 mask counts

// ---------------------------------------------------------------------------
// kPool: pure masked pool partial. grid 1024 (b = bid>>2, 64-row chunk bid&3),
// block 192. LDS = 256B only -> 10 blocks/CU, 30 waves/CU.
// ---------------------------------------------------------------------------
__global__ __launch_bounds__(192) void kPool(const float* __restrict__ lhs,
                                             const int* __restrict__ mask,
                                             float* __restrict__ part1,
                                             int* __restrict__ cntp) {
    const int bid = blockIdx.x;
    const int t = threadIdx.x;
    __shared__ float msk[64];

    const int b = bid >> 2, chunk = bid & 3, s0 = chunk * 64;
    if (t < 64) {
        const int mv = mask[b * S + s0 + t];
        msk[t] = (float)mv;
        int v = mv;
#pragma unroll
        for (int off = 32; off > 0; off >>= 1) v += __shfl_down(v, off, 64);
        if (t == 0) cntp[b * 4 + chunk] = v;
    }
    __syncthreads();

    const float4* src = (const float4*)lhs + (size_t)(b * S + s0) * H4 + t;
    float4 acc = make_float4(0.f, 0.f, 0.f, 0.f);
#pragma unroll 8
    for (int s = 0; s < 64; ++s) {
        const float m = msk[s];
        const float4 v = src[(size_t)s * H4];
        acc.x += v.x * m; acc.y += v.y * m; acc.z += v.z * m; acc.w += v.w * m;
    }
    ((float4*)part1)[(size_t)(b * 4 + chunk) * H4 + t] = acc;
}

// ---------------------------------------------------------------------------
// kC: blocks 0..255  : xS col-slice GEMM (pool-finalize inlined) + t_x
//                      partials + score-dot partials vs all 150 means.
//     blocks 256..407: t_m partials (means @ cov . means), no pool dependency.
// block 192 = 8 kg x 24 f4-cols.
// ---------------------------------------------------------------------------
__global__ __launch_bounds__(192) void kC(const float* __restrict__ part1,
                                          const int* __restrict__ cntp,
                                          const float* __restrict__ cov,
                                          const float* __restrict__ means,
                                          float* __restrict__ dp,
                                          float* __restrict__ tx_part,
                                          float* __restrict__ tm_part) {
    const int t = threadIdx.x;
    const int kg = t / 24, c4 = t % 24;
    __shared__ float xsl[8 * H];          // 24 KB
    __shared__ float4 red2[8][24];        // 3 KB
    __shared__ float4 xsf[8][24];         // 3 KB
    __shared__ float sred[8][3];

    if (blockIdx.x < 256) {
        const int rt = blockIdx.x >> 3, cs = blockIdx.x & 7;
        const int r0 = rt * 8, cb = cs * 24;

        // pool finalize into LDS
        for (int r = 0; r < 8; ++r) {
            const int row = r0 + r;
            const int cnt = cntp[row * 4] + cntp[row * 4 + 1] + cntp[row * 4 + 2] + cntp[row * 4 + 3];
            const float inv = 1.0f / fmaxf((float)cnt, 1e-9f);
            const float4* p = (const float4*)part1 + (size_t)row * 4 * H4 + t;
            const float4 a = p[0], b2 = p[H4], c2 = p[2 * H4], d2 = p[3 * H4];
            float4 v;
            v.x = (a.x + b2.x + c2.x + d2.x) * inv;
            v.y = (a.y + b2.y + c2.y + d2.y) * inv;
            v.z = (a.z + b2.z + c2.z + d2.z) * inv;
            v.w = (a.w + b2.w + c2.w + d2.w) * inv;
            ((float4*)xsl)[r * H4 + t] = v;
        }
        __syncthreads();

        float4 acc[8];
#pragma unroll
        for (int r = 0; r < 8; ++r) acc[r] = make_float4(0.f, 0.f, 0.f, 0.f);
        const float4* cov4 = (const float4*)cov + cb + c4;
#pragma unroll 4
        for (int kk = 0; kk < 96; ++kk) {
            const int k = kg * 96 + kk;
            const float4 cv = cov4[(size_t)k * H4];
#pragma unroll
            for (int r = 0; r < 8; ++r) {
                const float xv = xsl[r * H + k];
                acc[r].x += xv * cv.x; acc[r].y += xv * cv.y;
                acc[r].z += xv * cv.z; acc[r].w += xv * cv.w;
            }
        }

        float pdr[8];
#pragma unroll
        for (int r = 0; r < 8; ++r) pdr[r] = 0.f;
        for (int r = 0; r < 8; ++r) {
            red2[kg][c4] = acc[r];
            __syncthreads();
            if (kg == 0) {
                float4 s = red2[0][c4];
#pragma unroll
                for (int g = 1; g < 8; ++g) {
                    const float4 q = red2[g][c4];
                    s.x += q.x; s.y += q.y; s.z += q.z; s.w += q.w;
                }
                xsf[r][c4] = s;
                const float4 xv = ((float4*)xsl)[r * H4 + cb + c4];
                pdr[r] = s.x * xv.x + s.y * xv.y + s.z * xv.z + s.w * xv.w;
            }
            __syncthreads();
        }

        // t_x partials (lanes 0..23 hold contributions)
        if (t < 64) {
#pragma unroll
            for (int r = 0; r < 8; ++r) {
                float v = (t < 24) ? pdr[r] : 0.f;
#pragma unroll
                for (int off = 16; off > 0; off >>= 1) v += __shfl_down(v, off, 32);
                if (t == 0) tx_part[cs * 256 + r0 + r] = v;
            }
        }

        // score-dot partials: thread t = class c, stream means slice from L2
        if (t < C) {
            const float4* mu4 = (const float4*)means + (size_t)t * H4 + cb;
            float a8[8];
#pragma unroll
            for (int r = 0; r < 8; ++r) a8[r] = 0.f;
#pragma unroll 4
            for (int j = 0; j < 24; ++j) {
                const float4 mv = mu4[j];
#pragma unroll
                for (int r = 0; r < 8; ++r) {
                    const float4 x = xsf[r][j];
                    a8[r] += mv.x * x.x + mv.y * x.y + mv.z * x.z + mv.w * x.w;
                }
            }
#pragma unroll
            for (int r = 0; r < 8; ++r)
                dp[((size_t)(cs * 256) + (r0 + r)) * 150 + t] = a8[r];
        }
    } else {
        // ---- t_m partials: rows r0..r0+7 of means, f4-cols cb..cb+23, k-split 8 ----
        const int idx = blockIdx.x - 256;
        const int rt = idx >> 3, cs = idx & 7;
        const int r0 = rt * 8, cb = cs * 24;

        for (int r = 0; r < 8; ++r) {
            const int row = r0 + r;
            float4 v = make_float4(0.f, 0.f, 0.f, 0.f);
            if (row < C) v = ((const float4*)means)[(size_t)row * H4 + t];
            ((float4*)xsl)[r * H4 + t] = v;
        }
        __syncthreads();

        float4 acc[8];
#pragma unroll
        for (int r = 0; r < 8; ++r) acc[r] = make_float4(0.f, 0.f, 0.f, 0.f);
        const float4* cov4 = (const float4*)cov + cb + c4;
#pragma unroll 4
        for (int kk = 0; kk < 96; ++kk) {
            const int k = kg * 96 + kk;
            const float4 cv = cov4[(size_t)k * H4];
#pragma unroll
            for (int r = 0; r < 8; ++r) {
                const float xv = xsl[r * H + k];
                acc[r].x += xv * cv.x; acc[r].y += xv * cv.y;
                acc[r].z += xv * cv.z; acc[r].w += xv * cv.w;
            }
        }
        const int w = t >> 6;
#pragma unroll
        for (int r = 0; r < 8; ++r) {
            const float4 mu = ((float4*)xsl)[r * H4 + cb + c4];
            float pd = acc[r].x * mu.x + acc[r].y * mu.y + acc[r].z * mu.z + acc[r].w * mu.w;
#pragma unroll
            for (int off = 32; off > 0; off >>= 1) pd += __shfl_down(pd, off, 64);
            if ((t & 63) == 0) sred[r][w] = pd;
        }
        __syncthreads();
        if (t < 8) {
            const int row = r0 + t;
            if (row < C)
                tm_part[cs * 152 + row] = sred[t][0] + sred[t][1] + sred[t][2];
        }
    }
}

// ---------------------------------------------------------------------------
// kD: reduce partials -> scores + argmin. One block per b, 192 threads.
// ---------------------------------------------------------------------------
__global__ __launch_bounds__(192) void kD(const float* __restrict__ dp,
                                          const float* __restrict__ tx_part,
                                          const float* __restrict__ tm_part,
                                          float* __restrict__ out) {
    const int b = blockIdx.x, t = threadIdx.x;
    __shared__ float sv[192];
    __shared__ int si[192];

    float sc = INFINITY;
    if (t < C) {
        float d = 0.f;
#pragma unroll
        for (int j = 0; j < 8; ++j) d += dp[((size_t)(j * 256) + b) * 150 + t];
        float tx = 0.f;
#pragma unroll
        for (int j = 0; j < 8; ++j) tx += tx_part[j * 256 + b];
        float tm = 0.f;
#pragma unroll
        for (int j = 0; j < 8; ++j) tm += tm_part[j * 152 + t];
        sc = tx - 2.0f * d + tm;
        out[B + (size_t)t * B + b] = sc;
    }
    sv[t] = sc;
    si[t] = (t < C) ? t : 0x7fffffff;
    __syncthreads();
#pragma unroll
    for (int off = 96; off >= 3; off >>= 1) {
        if (t < off) {
            const float ov = sv[t + off];
            const int oi = si[t + off];
            if (ov < sv[t] || (ov == sv[t] && oi < si[t])) { sv[t] = ov; si[t] = oi; }
        }
        __syncthreads();
    }
    if (t == 0) {
        float bv = sv[0];
        int bi = si[0];
#pragma unroll
        for (int j = 1; j < 3; ++j)
            if (sv[j] < bv || (sv[j] == bv && si[j] < bi)) { bv = sv[j]; bi = si[j]; }
        out[b] = (float)bi;
    }
}

extern "C" void kernel_launch(void* const* d_in, const int* in_sizes, int n_in,
                              void* d_out, int out_size, void* d_ws, size_t ws_size,
                              hipStream_t stream) {
    const float* lhs   = (const float*)d_in[0];   // [B,S,H] f32
    const int*   mask  = (const int*)d_in[1];     // [B,S] i32
    const float* means = (const float*)d_in[2];   // [C,H] f32
    const float* cov   = (const float*)d_in[3];   // [H,H] f32
    float* out = (float*)d_out;

    char* ws = (char*)d_ws;
    float* part1   = (float*)(ws + 0);
    float* dp      = (float*)(ws + 3145728);
    float* tx_part = (float*)(ws + 4374528);
    float* tm_part = (float*)(ws + 4382720);
    int*   cntp    = (int*)  (ws + 4387584);

    kPool<<<dim3(1024), 192, 0, stream>>>(lhs, mask, part1, cntp);
    kC<<<dim3(256 + 152), 192, 0, stream>>>(part1, cntp, cov, means, dp, tx_part, tm_part);
    kD<<<dim3(256), 192, 0, stream>>>(dp, tx_part, tm_part, out);
}